// Round 13
// baseline (142.514 us; speedup 1.0000x reference)
//
#include <hip/hip_runtime.h>

typedef __attribute__((ext_vector_type(8))) __bf16 bf16x8;
typedef __attribute__((ext_vector_type(4))) float f32x4;

#define LOG2E 1.4426950408889634f

// ---- workspace byte offsets ----
// OTacc lives at 0. S slices live in d_out.
#define OTA_OFF  0ul          // OTacc: f32 [8][4096][128]
#define TT_OFF   16777216ul   // Tt  : bf16 [8][2048][256]  (x_theta, n-major)
#define PT_OFF   25165824ul   // Pt  : bf16 [8][2048][256]  (x_phi, n-major)
#define G_OFF    33554432ul   // G   : bf16 [8][256][2048]  (x_g, c-major; scaled per-slice)
#define W3_OFF   41943040ul   // W3  : bf16 [384][256]
#define WM_OFF   42139648ul   // Wm  : bf16 [256][128]
#define ID_OFF   42205184ul   // invD: f32  [8][2048]
#define PART_OFF 42270720ul   // PART: f32  [8][32][1024] per-slice column partials (1 MB)
#define WS_NEED  44367872ul

// async global->LDS, 16B per lane, wave-uniform LDS base
__device__ __forceinline__ void gload16(const __bf16* g, __bf16* l){
  __builtin_amdgcn_global_load_lds((const __attribute__((address_space(1))) void*)g,
                                   (__attribute__((address_space(3))) void*)l, 16, 0, 0);
}

// ---------------- weights cast ----------------
__global__ __launch_bounds__(256) void k_weights(const float* wt, const float* wp,
                                                 const float* wg, const float* wm,
                                                 __bf16* W3, __bf16* Wm){
  int idx = blockIdx.x*256 + threadIdx.x;
  if (idx < 98304){
    float v = (idx < 32768) ? wt[idx] : (idx < 65536) ? wp[idx - 32768] : wg[idx - 65536];
    W3[idx] = (__bf16)v;
  } else if (idx < 131072){
    Wm[idx - 98304] = (__bf16)wm[idx - 98304];
  }
}

// ---------------- fused transpose + conv3: x(f32, c-major) -> Tt/Pt/G ----------------
__global__ __launch_bounds__(512, 2) void k_conv3x(const float* x, const __bf16* W3,
                                                   __bf16* Tt, __bf16* Pt, __bf16* G){
  __shared__ __bf16 As[128*256];      // 64 KB swizzled A
  __shared__ __bf16 Bs[2][64*256];    // 64 KB dbuf W3 o-tiles
  __shared__ float  tf[64*65];        // 16.3 KB transpose tile
  int bid = blockIdx.x;
  int b = bid & 7, m = bid >> 3, p0 = m*128;   // batch -> XCD
  int tid = threadIdx.x, lane = tid & 63, w = tid >> 6;
  int lr = lane & 15, kq = lane >> 4;
  int pw = w & 1, ow4 = w >> 1;
  const float* xb = x + (size_t)b*256*4096 + p0;
  int sRow2 = lane >> 5, sSlot = lane & 31;
  // prefetch B o-tile 0 (lands during transpose)
  #pragma unroll
  for (int u = 0; u < 4; ++u){
    int row = u*16 + w*2 + sRow2;
    gload16(W3 + (size_t)row*256 + ((sSlot ^ (row & 7))*8), &Bs[0][(u*16 + w*2)*256]);
  }
  // phase 1: transpose-convert 8 subtiles [64c][64p]
  #pragma unroll
  for (int st = 0; st < 8; ++st){
    int ct = st >> 1, pt = st & 1;
    int c0 = ct*64, ps = pt*64;
    #pragma unroll
    for (int u = 0; u < 2; ++u){
      int idx = u*512 + tid;
      int row = idx >> 4, col4 = (idx & 15)*4;
      f32x4 v = *(const f32x4*)(xb + (size_t)(c0 + row)*4096 + ps + col4);
      #pragma unroll
      for (int e = 0; e < 4; ++e) tf[row*65 + col4 + e] = v[e];
    }
    __syncthreads();
    {
      int pl = tid & 63, slot8 = tid >> 6;
      __bf16 pk[8];
      #pragma unroll
      for (int e = 0; e < 8; ++e) pk[e] = (__bf16)tf[(slot8*8 + e)*65 + pl];
      int row = ps + pl, slotIdx = ct*8 + slot8;
      *(uint4*)&As[row*256 + ((slotIdx ^ (row & 7))*8)] = *(const uint4*)pk;
    }
    __syncthreads();
  }
  // phase 2: hoist this wave's A fragments (static indices)
  bf16x8 aReg[4][8];                   // [fm][kc*2+ks]
  #pragma unroll
  for (int fm = 0; fm < 4; ++fm){
    int ar = pw*64 + fm*16 + lr;
    #pragma unroll
    for (int sl = 0; sl < 8; ++sl){
      int slotA = (sl >> 1)*8 + (sl & 1)*4 + kq;
      aReg[fm][sl] = *(const bf16x8*)&As[ar*256 + ((slotA ^ (ar & 7))*8)];
    }
  }
  // phase 3: 6 o-tiles
  for (int ot = 0; ot < 6; ++ot){
    if (ot < 5){
      int buf = (ot + 1) & 1;
      #pragma unroll
      for (int u = 0; u < 4; ++u){
        int row = u*16 + w*2 + sRow2;
        gload16(W3 + (size_t)((ot+1)*64 + row)*256 + ((sSlot ^ (row & 7))*8),
                &Bs[buf][(u*16 + w*2)*256]);
      }
    }
    const __bf16* Bc = &Bs[ot & 1][0];
    f32x4 acc[4] = {};
    #pragma unroll
    for (int kc = 0; kc < 4; ++kc)
      #pragma unroll
      for (int ks = 0; ks < 2; ++ks){
        int slotB = kc*8 + ks*4 + kq;
        int br = ow4*16 + lr;
        bf16x8 bf = *(const bf16x8*)&Bc[br*256 + ((slotB ^ (br & 7))*8)];
        #pragma unroll
        for (int fm = 0; fm < 4; ++fm)
          acc[fm] = __builtin_amdgcn_mfma_f32_16x16x32_bf16(aReg[fm][kc*2+ks], bf, acc[fm], 0, 0, 0);
      }
    // scatter per the reshape-view: flat = o*4096+p -> c = 2o+(p>>11), n = p&2047
    #pragma unroll
    for (int fm = 0; fm < 4; ++fm)
      #pragma unroll
      for (int r = 0; r < 4; ++r){
        int p = p0 + pw*64 + fm*16 + kq*4 + r;
        int o = ot*64 + ow4*16 + lr;
        __bf16 v = (__bf16)acc[fm][r];
        int i = p & 2047, ph = p >> 11;
        if (o < 128)      Tt[((size_t)b*2048 + i)*256 + 2*o + ph] = v;
        else if (o < 256) Pt[((size_t)b*2048 + i)*256 + 2*(o-128) + ph] = v;
        else              G [((size_t)b*256 + 2*(o-256) + ph)*2048 + i] = v;
      }
    __syncthreads();
  }
}

// ---------------- GEMM1: S = exp(Tt . Pt^T) for j-slice, + column partial sums ----------------
// ZERO-barrier wave-autonomous v3: A-frags gathered global->VGPR once (no A LDS);
// each wave streams its 4 j-chunks through a wave-private 4-deep ring, prefetch
// issued 3 steps ahead, counted vmcnt (8 steady / 4,0 peeled tail). 16 steps/wave.
__global__ __launch_bounds__(512, 2) void k_sexp(const __bf16* Tt, const __bf16* Pt,
                                                 __bf16* S, float* PART, int js0){
  __shared__ __bf16 Bs[8][4][2048];    // 128 KB: per-wave 4-ring of [32j][64k] chunks
  int bid = blockIdx.x;
  int b = bid & 7, m = bid >> 3, m0 = m*64;   // batch -> XCD
  int tid = threadIdx.x, lane = tid & 63, w = tid >> 6;
  int lr = lane & 15, kq = lane >> 4;
  const __bf16* Tb = Tt + ((size_t)b*2048 + m0)*256;
  const __bf16* Pb = Pt + ((size_t)b*2048 + js0)*256;
  __bf16* Sb = S + ((size_t)b*2048 + m0)*1024;
  // ---- A fragments: one-time direct gather to VGPR (oldest vmem ops; retired by step-0 wait) ----
  bf16x8 aReg[4][8];                   // [fm][kc*2+ks]
  #pragma unroll
  for (int fm = 0; fm < 4; ++fm)
    #pragma unroll
    for (int sl = 0; sl < 8; ++sl)
      aReg[fm][sl] = *(const bf16x8*)(Tb + (size_t)(fm*16 + lr)*256
                                      + (sl >> 1)*64 + (sl & 1)*32 + kq*8);
  // ---- B prologue: steps 0,1,2 into rings 0,1,2 (wave-private) ----
  int bRow = lane >> 3, bSlot = lane & 7;      // 8 rows x 8 slots per instr
  #pragma unroll
  for (int s0 = 0; s0 < 3; ++s0){
    int j0 = w*32, kc = s0;                    // q=0 chunk, kc=s0
    #pragma unroll
    for (int u = 0; u < 4; ++u){
      int row = j0 + u*8 + bRow;
      gload16(Pb + (size_t)row*256 + kc*64 + ((bSlot ^ (row & 7))*8), &Bs[w][s0][u*512]);
    }
  }
  for (int q = 0; q < 4; ++q){
    int j0 = (w + q*8)*32;
    f32x4 acc[4][2] = {};
    #pragma unroll
    for (int kc = 0; kc < 4; ++kc){
      int s = q*4 + kc;
      // counted wait: steady vmcnt(8) retires step-s's 4 loads (12 outstanding at entry)
      if (s < 14)       asm volatile("s_waitcnt vmcnt(8)" ::: "memory");
      else if (s == 14) asm volatile("s_waitcnt vmcnt(4)" ::: "memory");
      else              asm volatile("s_waitcnt vmcnt(0)" ::: "memory");
      // prefetch step s+3 into ring (s+3)&3 (that buffer was consumed at step s-1)
      if (s + 3 < 16){
        int s2 = s + 3, q2 = s2 >> 2, kc2 = s2 & 3;
        int j02 = (w + q2*8)*32;
        #pragma unroll
        for (int u = 0; u < 4; ++u){
          int row = j02 + u*8 + bRow;
          gload16(Pb + (size_t)row*256 + kc2*64 + ((bSlot ^ (row & 7))*8),
                  &Bs[w][s2 & 3][u*512]);
        }
      }
      const __bf16* Bc = &Bs[w][s & 3][0];
      #pragma unroll
      for (int ks = 0; ks < 2; ++ks){
        int slotB = ks*4 + kq;
        bf16x8 bf[2];
        #pragma unroll
        for (int fn = 0; fn < 2; ++fn){
          int br = fn*16 + lr;
          bf[fn] = *(const bf16x8*)&Bc[br*64 + ((slotB ^ (br & 7))*8)];
        }
        #pragma unroll
        for (int fm = 0; fm < 4; ++fm)
          #pragma unroll
          for (int fn = 0; fn < 2; ++fn)
            acc[fm][fn] = __builtin_amdgcn_mfma_f32_16x16x32_bf16(aReg[fm][kc*2+ks], bf[fn], acc[fm][fn], 0, 0, 0);
      }
    }
    // chunk epilogue: exp -> direct 2B stores (chunk covers full 64B lines), column sums.
    // Stores overlap the in-flight loads of the next chunk.
    #pragma unroll
    for (int fn = 0; fn < 2; ++fn){
      float v = 0.f;
      #pragma unroll
      for (int fm = 0; fm < 4; ++fm){
        #pragma unroll
        for (int r = 0; r < 4; ++r){
          float e = exp2f(acc[fm][fn][r] * LOG2E);
          v += e;
          Sb[(size_t)(fm*16 + kq*4 + r)*1024 + j0 + fn*16 + lr] = (__bf16)e;
        }
      }
      v += __shfl_xor(v, 16);
      v += __shfl_xor(v, 32);
      if (kq == 0)
        PART[((size_t)b*32 + m)*1024 + j0 + fn*16 + lr] = v;
    }
  }
}

// ---------------- reduce partials -> invD = 1/D for slice ----------------
__global__ __launch_bounds__(256) void k_invd(const float* PART, float* invD, int js0){
  int bid = blockIdx.x;                  // 32
  int b = bid & 7, seg = bid >> 3;
  int jl = seg*256 + threadIdx.x;        // 0..1023
  float s = 0.f;
  #pragma unroll
  for (int it = 0; it < 32; ++it) s += PART[((size_t)b*32 + it)*1024 + jl];
  invD[(size_t)b*2048 + js0 + jl] = 1.0f / s;
}

// ---------------- scale G slice columns in place ----------------
__global__ __launch_bounds__(256) void k_gscale(__bf16* G, const float* invD, int js0){
  int bid = blockIdx.x;                  // 2048 = 8 b * 256 c
  int b = bid >> 8, c = bid & 255;
  int jl = threadIdx.x * 4;
  __bf16* gp = G + ((size_t)b*256 + c)*2048 + js0 + jl;
  const float* dp = invD + (size_t)b*2048 + js0 + jl;
  f32x4 d = *(const f32x4*)dp;
  __bf16 gv[4];
  *(uint2*)gv = *(const uint2*)gp;
  #pragma unroll
  for (int e = 0; e < 4; ++e) gv[e] = (__bf16)((float)gv[e] * d[e]);
  *(uint2*)gp = *(const uint2*)gv;
}

// ---------------- GEMM2: OTacc (+)= S_slice . G'^T ----------------
__global__ __launch_bounds__(256) void k_pv(const __bf16* S, const __bf16* G,
                                            float* OTacc, int js0, int first){
  __shared__ __bf16 sA[3][128*64];      // 48 KB
  __shared__ __bf16 sB[3][64*64];       // 24 KB
  int bid = blockIdx.x;
  int b = bid & 7, r2 = bid >> 3;
  int n = r2 & 3, m = r2 >> 2;          // consecutive bids share the S A-panel
  int m0 = m*128, n0 = n*64;
  int tid = threadIdx.x, lane = tid & 63, w = tid >> 6;
  int lr = lane & 15, kq = lane >> 4;
  int wm = w >> 1, wn = w & 1;
  const __bf16* Ab = S + ((size_t)b*2048 + m0)*1024;            // lda 1024
  const __bf16* Bb = G + ((size_t)b*256 + n0)*2048 + js0;       // ldb 2048
  int bRow = lane >> 3, bSlot = lane & 7;
  f32x4 acc[4][2] = {};
  #pragma unroll
  for (int t0 = 0; t0 < 2; ++t0){
    #pragma unroll
    for (int u = 0; u < 4; ++u){
      int row = u*32 + w*8 + bRow;
      gload16(Ab + (size_t)row*1024 + t0*64 + ((bSlot ^ (row & 7))*8),
              &sA[t0][u*2048 + w*512]);
    }
    #pragma unroll
    for (int u = 0; u < 2; ++u){
      int row = u*32 + w*8 + bRow;
      gload16(Bb + (size_t)row*2048 + t0*64 + ((bSlot ^ (row & 7))*8),
              &sB[t0][u*2048 + w*512]);
    }
  }
  for (int t = 0; t < 16; ++t){
    if (t == 15) asm volatile("s_waitcnt vmcnt(0)" ::: "memory");
    else         asm volatile("s_waitcnt vmcnt(6)" ::: "memory");
    __builtin_amdgcn_s_barrier();
    if (t + 2 < 16){
      int t2 = t + 2, bf2 = t2 % 3, k0 = t2*64;
      #pragma unroll
      for (int u = 0; u < 4; ++u){
        int row = u*32 + w*8 + bRow;
        gload16(Ab + (size_t)row*1024 + k0 + ((bSlot ^ (row & 7))*8),
                &sA[bf2][u*2048 + w*512]);
      }
      #pragma unroll
      for (int u = 0; u < 2; ++u){
        int row = u*32 + w*8 + bRow;
        gload16(Bb + (size_t)row*2048 + k0 + ((bSlot ^ (row & 7))*8),
                &sB[bf2][u*2048 + w*512]);
      }
    }
    const __bf16* Ac = &sA[t % 3][0];
    const __bf16* Bc = &sB[t % 3][0];
    #pragma unroll
    for (int ks = 0; ks < 2; ++ks){
      int slot = ks*4 + kq;
      bf16x8 af[4], bf[2];
      #pragma unroll
      for (int fm = 0; fm < 4; ++fm){
        int ar = wm*64 + fm*16 + lr;
        af[fm] = *(const bf16x8*)&Ac[ar*64 + ((slot ^ (ar & 7))*8)];
      }
      #pragma unroll
      for (int fn = 0; fn < 2; ++fn){
        int br = wn*32 + fn*16 + lr;
        bf[fn] = *(const bf16x8*)&Bc[br*64 + ((slot ^ (br & 7))*8)];
      }
      #pragma unroll
      for (int fm = 0; fm < 4; ++fm)
        #pragma unroll
        for (int fn = 0; fn < 2; ++fn)
          acc[fm][fn] = __builtin_amdgcn_mfma_f32_16x16x32_bf16(af[fm], bf[fn], acc[fm][fn], 0, 0, 0);
    }
  }
  float* Ob = OTacc + (size_t)b*4096*128;
  if (first){
    #pragma unroll
    for (int fm = 0; fm < 4; ++fm)
      #pragma unroll
      for (int fn = 0; fn < 2; ++fn)
        #pragma unroll
        for (int r = 0; r < 4; ++r){
          int i = m0 + wm*64 + fm*16 + kq*4 + r;
          int c = n0 + wn*32 + fn*16 + lr;
          Ob[(size_t)(((c & 1) << 11) + i)*128 + (c >> 1)] = acc[fm][fn][r];
        }
  } else {
    #pragma unroll
    for (int fm = 0; fm < 4; ++fm)
      #pragma unroll
      for (int fn = 0; fn < 2; ++fn)
        #pragma unroll
        for (int r = 0; r < 4; ++r){
          int i = m0 + wm*64 + fm*16 + kq*4 + r;
          int c = n0 + wn*32 + fn*16 + lr;
          size_t idx = (size_t)(((c & 1) << 11) + i)*128 + (c >> 1);
          Ob[idx] += acc[fm][fn][r];
        }
  }
}

// ---------------- mask conv + residual: OTacc(4096x128 f32) * Wm^T(256x128) + x ----------------
__global__ __launch_bounds__(256) void k_mask(const float* OTacc, const __bf16* Wm,
                                              const float* x, float* out){
  __shared__ __bf16 As[128*72];
  __shared__ __bf16 Bs[64*72];
  int b = blockIdx.z, p0 = blockIdx.x*128, o0 = blockIdx.y*64;
  int tid = threadIdx.x, lane = tid & 63, wave = tid >> 6;
  int wm = wave >> 1, wn = wave & 1;
  f32x4 acc[4][2] = {};
  const float* Ab = OTacc + ((size_t)b*4096 + p0)*128;
  const __bf16* Bb = Wm + (size_t)o0*128;
  for (int kc = 0; kc < 2; ++kc){
    int k0 = kc*64;
    #pragma unroll
    for (int it = 0; it < 8; ++it){
      int idx = it*256 + tid;
      int row = idx >> 4, c4 = (idx & 15)*4;
      f32x4 vv = *(const f32x4*)(Ab + (size_t)row*128 + k0 + c4);
      __bf16 tmp[4];
      #pragma unroll
      for (int e = 0; e < 4; ++e) tmp[e] = (__bf16)vv[e];
      *(uint2*)&As[row*72 + c4] = *(const uint2*)tmp;
    }
    #pragma unroll
    for (int itc = 0; itc < 2; ++itc){
      int s = tid + itc*256, row = s >> 3, sk = s & 7;
      *(uint4*)&Bs[row*72 + sk*8] = *(const uint4*)(Bb + (size_t)row*128 + k0 + sk*8);
    }
    __syncthreads();
    #pragma unroll
    for (int ks = 0; ks < 2; ++ks){
      int koff = ks*32 + (lane>>4)*8;
      bf16x8 af[4], bfr[2];
      #pragma unroll
      for (int fm = 0; fm < 4; ++fm)
        af[fm] = *(const bf16x8*)&As[(wm*64 + fm*16 + (lane&15))*72 + koff];
      #pragma unroll
      for (int fn = 0; fn < 2; ++fn)
        bfr[fn] = *(const bf16x8*)&Bs[(wn*32 + fn*16 + (lane&15))*72 + koff];
      #pragma unroll
      for (int fm = 0; fm < 4; ++fm)
        #pragma unroll
        for (int fn = 0; fn < 2; ++fn)
          acc[fm][fn] = __builtin_amdgcn_mfma_f32_16x16x32_bf16(af[fm], bfr[fn], acc[fm][fn], 0, 0, 0);
    }
    __syncthreads();
  }
  #pragma unroll
  for (int fm = 0; fm < 4; ++fm)
    #pragma unroll
    for (int fn = 0; fn < 2; ++fn){
      int pb = p0 + wm*64 + fm*16 + (lane>>4)*4;
      int o = o0 + wn*32 + fn*16 + (lane&15);
      size_t idx = ((size_t)b*256 + o)*4096 + pb;
      f32x4 xv = *(const f32x4*)(x + idx);
      f32x4 ov = acc[fm][fn] + xv;
      *(f32x4*)(out + idx) = ov;
    }
}

extern "C" void kernel_launch(void* const* d_in, const int* in_sizes, int n_in,
                              void* d_out, int out_size, void* d_ws, size_t ws_size,
                              hipStream_t stream){
  if (ws_size < WS_NEED) return;  // workspace too small; fail visibly
  const float* x  = (const float*)d_in[0];
  const float* wt = (const float*)d_in[1];
  const float* wp = (const float*)d_in[2];
  const float* wg = (const float*)d_in[3];
  const float* wm = (const float*)d_in[4];
  char* ws = (char*)d_ws;
  float* OTacc = (float*)(ws + OTA_OFF);
  __bf16* Tt   = (__bf16*)(ws + TT_OFF);
  __bf16* Pt   = (__bf16*)(ws + PT_OFF);
  __bf16* G    = (__bf16*)(ws + G_OFF);
  __bf16* W3   = (__bf16*)(ws + W3_OFF);
  __bf16* Wm   = (__bf16*)(ws + WM_OFF);
  float* invD  = (float*)(ws + ID_OFF);
  float* PART  = (float*)(ws + PART_OFF);
  __bf16* S    = (__bf16*)d_out;           // S slice scratch lives in d_out
  float* out   = (float*)d_out;

  k_weights<<<512, 256, 0, stream>>>(wt, wp, wg, wm, W3, Wm);
  k_conv3x<<<256, 512, 0, stream>>>(x, W3, Tt, Pt, G);
  for (int s = 0; s < 2; ++s){
    int js0 = s * 1024;
    k_sexp<<<256, 512, 0, stream>>>(Tt, Pt, S, PART, js0);
    k_invd<<<32, 256, 0, stream>>>(PART, invD, js0);
    k_gscale<<<2048, 256, 0, stream>>>(G, invD, js0);
    k_pv<<<512, 256, 0, stream>>>(S, G, OTacc, js0, s == 0 ? 1 : 0);
  }
  k_mask<<<dim3(32, 4, 8), 256, 0, stream>>>(OTacc, Wm, x, out);
}

// Round 14
// 134.352 us; speedup vs baseline: 1.0608x; 1.0608x over previous
//
#include <hip/hip_runtime.h>

typedef __attribute__((ext_vector_type(8))) __bf16 bf16x8;
typedef __attribute__((ext_vector_type(4))) float f32x4;

#define LOG2E 1.4426950408889634f

// ---- workspace byte offsets ----
// OTacc lives at 0. S slices live in d_out.
#define OTA_OFF  0ul          // OTacc: f32 [8][4096][128]
#define TT_OFF   16777216ul   // Tt  : bf16 [8][2048][256]  (x_theta, n-major)
#define PT_OFF   25165824ul   // Pt  : bf16 [8][2048][256]  (x_phi, n-major)
#define G_OFF    33554432ul   // G   : bf16 [8][256][2048]  (x_g, c-major; scaled per-slice)
#define W3_OFF   41943040ul   // W3  : bf16 [384][256]
#define WM_OFF   42139648ul   // Wm  : bf16 [256][128]
#define ID_OFF   42205184ul   // invD: f32  [8][2048]
#define PART_OFF 42270720ul   // PART: f32  [8][32][1024] per-slice column partials (1 MB)
#define WS_NEED  44367872ul

// async global->LDS, 16B per lane, wave-uniform LDS base
__device__ __forceinline__ void gload16(const __bf16* g, __bf16* l){
  __builtin_amdgcn_global_load_lds((const __attribute__((address_space(1))) void*)g,
                                   (__attribute__((address_space(3))) void*)l, 16, 0, 0);
}

// ---------------- weights cast ----------------
__global__ __launch_bounds__(256) void k_weights(const float* wt, const float* wp,
                                                 const float* wg, const float* wm,
                                                 __bf16* W3, __bf16* Wm){
  int idx = blockIdx.x*256 + threadIdx.x;
  if (idx < 98304){
    float v = (idx < 32768) ? wt[idx] : (idx < 65536) ? wp[idx - 32768] : wg[idx - 65536];
    W3[idx] = (__bf16)v;
  } else if (idx < 131072){
    Wm[idx - 98304] = (__bf16)wm[idx - 98304];
  }
}

// ---------------- fused transpose + conv3: x(f32, c-major) -> Tt/Pt/G ----------------
// Block = (b, 128-p tile); grid 256 = 1 block/CU. 512 thr / 8 waves (pw 2 x ow4 4).
__global__ __launch_bounds__(512, 2) void k_conv3x(const float* x, const __bf16* W3,
                                                   __bf16* Tt, __bf16* Pt, __bf16* G){
  __shared__ __bf16 As[128*256];      // 64 KB swizzled A
  __shared__ __bf16 Bs[2][64*256];    // 64 KB dbuf W3 o-tiles
  __shared__ float  tf[64*65];        // 16.3 KB transpose tile
  int bid = blockIdx.x;
  int b = bid & 7, m = bid >> 3, p0 = m*128;   // batch -> XCD
  int tid = threadIdx.x, lane = tid & 63, w = tid >> 6;
  int lr = lane & 15, kq = lane >> 4;
  int pw = w & 1, ow4 = w >> 1;
  const float* xb = x + (size_t)b*256*4096 + p0;
  int sRow2 = lane >> 5, sSlot = lane & 31;
  // prefetch B o-tile 0 (lands during transpose)
  #pragma unroll
  for (int u = 0; u < 4; ++u){
    int row = u*16 + w*2 + sRow2;
    gload16(W3 + (size_t)row*256 + ((sSlot ^ (row & 7))*8), &Bs[0][(u*16 + w*2)*256]);
  }
  // phase 1: transpose-convert 8 subtiles [64c][64p]
  #pragma unroll
  for (int st = 0; st < 8; ++st){
    int ct = st >> 1, pt = st & 1;
    int c0 = ct*64, ps = pt*64;
    #pragma unroll
    for (int u = 0; u < 2; ++u){
      int idx = u*512 + tid;
      int row = idx >> 4, col4 = (idx & 15)*4;
      f32x4 v = *(const f32x4*)(xb + (size_t)(c0 + row)*4096 + ps + col4);
      #pragma unroll
      for (int e = 0; e < 4; ++e) tf[row*65 + col4 + e] = v[e];
    }
    __syncthreads();
    {
      int pl = tid & 63, slot8 = tid >> 6;
      __bf16 pk[8];
      #pragma unroll
      for (int e = 0; e < 8; ++e) pk[e] = (__bf16)tf[(slot8*8 + e)*65 + pl];
      int row = ps + pl, slotIdx = ct*8 + slot8;
      *(uint4*)&As[row*256 + ((slotIdx ^ (row & 7))*8)] = *(const uint4*)pk;
    }
    __syncthreads();
  }
  // phase 2: hoist this wave's A fragments (static indices)
  bf16x8 aReg[4][8];                   // [fm][kc*2+ks]
  #pragma unroll
  for (int fm = 0; fm < 4; ++fm){
    int ar = pw*64 + fm*16 + lr;
    #pragma unroll
    for (int sl = 0; sl < 8; ++sl){
      int slotA = (sl >> 1)*8 + (sl & 1)*4 + kq;
      aReg[fm][sl] = *(const bf16x8*)&As[ar*256 + ((slotA ^ (ar & 7))*8)];
    }
  }
  // phase 3: 6 o-tiles
  for (int ot = 0; ot < 6; ++ot){
    if (ot < 5){
      int buf = (ot + 1) & 1;
      #pragma unroll
      for (int u = 0; u < 4; ++u){
        int row = u*16 + w*2 + sRow2;
        gload16(W3 + (size_t)((ot+1)*64 + row)*256 + ((sSlot ^ (row & 7))*8),
                &Bs[buf][(u*16 + w*2)*256]);
      }
    }
    const __bf16* Bc = &Bs[ot & 1][0];
    f32x4 acc[4] = {};
    #pragma unroll
    for (int kc = 0; kc < 4; ++kc)
      #pragma unroll
      for (int ks = 0; ks < 2; ++ks){
        int slotB = kc*8 + ks*4 + kq;
        int br = ow4*16 + lr;
        bf16x8 bf = *(const bf16x8*)&Bc[br*256 + ((slotB ^ (br & 7))*8)];
        #pragma unroll
        for (int fm = 0; fm < 4; ++fm)
          acc[fm] = __builtin_amdgcn_mfma_f32_16x16x32_bf16(aReg[fm][kc*2+ks], bf, acc[fm], 0, 0, 0);
      }
    // scatter per the reshape-view: flat = o*4096+p -> c = 2o+(p>>11), n = p&2047
    #pragma unroll
    for (int fm = 0; fm < 4; ++fm)
      #pragma unroll
      for (int r = 0; r < 4; ++r){
        int p = p0 + pw*64 + fm*16 + kq*4 + r;
        int o = ot*64 + ow4*16 + lr;
        __bf16 v = (__bf16)acc[fm][r];
        int i = p & 2047, ph = p >> 11;
        if (o < 128)      Tt[((size_t)b*2048 + i)*256 + 2*o + ph] = v;
        else if (o < 256) Pt[((size_t)b*2048 + i)*256 + 2*(o-128) + ph] = v;
        else              G [((size_t)b*256 + 2*(o-256) + ph)*2048 + i] = v;
      }
    __syncthreads();
  }
}

// ---------------- GEMM1: S = exp(Tt . Pt^T) for j-slice, + column partial sums ----------------
// Wave-autonomous + A-register-hoist (R11/R12 proven) with store-aware counted vmcnt:
// chunk epilogue issues ~34 global stores AFTER the next chunk's first prefetches; vmcnt
// retires in issue order, so kc<2 steps use vmcnt(36) (target loads are OLDER than the
// stores) instead of vmcnt(4), letting stores drain in background instead of stalling.
__global__ __launch_bounds__(512, 2) void k_sexp(const __bf16* Tt, const __bf16* Pt,
                                                 __bf16* S, float* PART, int js0){
  __shared__ __bf16 As[64*256];        // 32 KB shared A (swizzled)
  __shared__ __bf16 Bs[8][3][2048];    // 96 KB: per-wave 3-ring of [32j][64k] chunks
  int bid = blockIdx.x;
  int b = bid & 7, m = bid >> 3, m0 = m*64;   // batch -> XCD
  int tid = threadIdx.x, lane = tid & 63, w = tid >> 6;
  int lr = lane & 15, kq = lane >> 4;
  const __bf16* Ab = Tt + ((size_t)b*2048 + m0)*256;
  const __bf16* Pb = Pt + ((size_t)b*2048 + js0)*256;
  __bf16* Sb = S + ((size_t)b*2048 + m0)*1024;
  {
    int aRow = lane >> 5, aSlot = lane & 31;
    #pragma unroll
    for (int u = 0; u < 4; ++u){
      int row = w*8 + u*2 + aRow;
      gload16(Ab + (size_t)row*256 + ((aSlot ^ (row & 7))*8), &As[w*2048 + u*512]);
    }
  }
  int bRow = lane >> 3, bSlot = lane & 7;
  #pragma unroll
  for (int s0 = 0; s0 < 2; ++s0){
    int j0 = (w + (s0 >> 2)*8)*32, kc = s0 & 3;
    #pragma unroll
    for (int u = 0; u < 4; ++u){
      int row = j0 + u*8 + bRow;
      gload16(Pb + (size_t)row*256 + kc*64 + ((bSlot ^ (row & 7))*8), &Bs[w][s0][u*512]);
    }
  }
  __syncthreads();
  bf16x8 aReg[4][8];
  #pragma unroll
  for (int fm = 0; fm < 4; ++fm){
    int ar = fm*16 + lr;
    #pragma unroll
    for (int sl = 0; sl < 8; ++sl){
      int slotA = (sl >> 1)*8 + (sl & 1)*4 + kq;
      aReg[fm][sl] = *(const bf16x8*)&As[ar*256 + ((slotA ^ (ar & 7))*8)];
    }
  }
  for (int q = 0; q < 4; ++q){
    int j0 = (w + q*8)*32;
    f32x4 acc[4][2] = {};
    #pragma unroll
    for (int kc = 0; kc < 4; ++kc){
      int s = q*4 + kc;
      // store-aware counted waits: target loads are older than epilogue stores for kc<2
      if (s == 15)     asm volatile("s_waitcnt vmcnt(0)" ::: "memory");
      else if (kc < 2) asm volatile("s_waitcnt vmcnt(36)" ::: "memory");
      else             asm volatile("s_waitcnt vmcnt(4)" ::: "memory");
      if (s + 2 < 16){
        int s2 = s + 2, q2 = s2 >> 2, kc2 = s2 & 3, rb = s2 % 3;
        int j02 = (w + q2*8)*32;
        #pragma unroll
        for (int u = 0; u < 4; ++u){
          int row = j02 + u*8 + bRow;
          gload16(Pb + (size_t)row*256 + kc2*64 + ((bSlot ^ (row & 7))*8), &Bs[w][rb][u*512]);
        }
      }
      const __bf16* Bc = &Bs[w][s % 3][0];
      #pragma unroll
      for (int ks = 0; ks < 2; ++ks){
        int slotB = ks*4 + kq;
        bf16x8 bf[2];
        #pragma unroll
        for (int fn = 0; fn < 2; ++fn){
          int br = fn*16 + lr;
          bf[fn] = *(const bf16x8*)&Bc[br*64 + ((slotB ^ (br & 7))*8)];
        }
        #pragma unroll
        for (int fm = 0; fm < 4; ++fm)
          #pragma unroll
          for (int fn = 0; fn < 2; ++fn)
            acc[fm][fn] = __builtin_amdgcn_mfma_f32_16x16x32_bf16(aReg[fm][kc*2+ks], bf[fn], acc[fm][fn], 0, 0, 0);
      }
    }
    // chunk epilogue: exp -> direct 2B stores (chunk covers full 64B lines), column sums
    #pragma unroll
    for (int fn = 0; fn < 2; ++fn){
      float v = 0.f;
      #pragma unroll
      for (int fm = 0; fm < 4; ++fm){
        #pragma unroll
        for (int r = 0; r < 4; ++r){
          float e = exp2f(acc[fm][fn][r] * LOG2E);
          v += e;
          Sb[(size_t)(fm*16 + kq*4 + r)*1024 + j0 + fn*16 + lr] = (__bf16)e;
        }
      }
      v += __shfl_xor(v, 16);
      v += __shfl_xor(v, 32);
      if (kq == 0)
        PART[((size_t)b*32 + m)*1024 + j0 + fn*16 + lr] = v;
    }
  }
}

// ---------------- reduce partials -> invD = 1/D for slice ----------------
__global__ __launch_bounds__(256) void k_invd(const float* PART, float* invD, int js0){
  int bid = blockIdx.x;                  // 32
  int b = bid & 7, seg = bid >> 3;
  int jl = seg*256 + threadIdx.x;        // 0..1023
  float s = 0.f;
  #pragma unroll
  for (int it = 0; it < 32; ++it) s += PART[((size_t)b*32 + it)*1024 + jl];
  invD[(size_t)b*2048 + js0 + jl] = 1.0f / s;
}

// ---------------- scale G slice columns in place ----------------
__global__ __launch_bounds__(256) void k_gscale(__bf16* G, const float* invD, int js0){
  int bid = blockIdx.x;                  // 2048 = 8 b * 256 c
  int b = bid >> 8, c = bid & 255;
  int jl = threadIdx.x * 4;
  __bf16* gp = G + ((size_t)b*256 + c)*2048 + js0 + jl;
  const float* dp = invD + (size_t)b*2048 + js0 + jl;
  f32x4 d = *(const f32x4*)dp;
  __bf16 gv[4];
  *(uint2*)gv = *(const uint2*)gp;
  #pragma unroll
  for (int e = 0; e < 4; ++e) gv[e] = (__bf16)((float)gv[e] * d[e]);
  *(uint2*)gp = *(const uint2*)gv;
}

// ---------------- GEMM2: OTacc (+)= S_slice . G'^T ----------------
__global__ __launch_bounds__(256) void k_pv(const __bf16* S, const __bf16* G,
                                            float* OTacc, int js0, int first){
  __shared__ __bf16 sA[3][128*64];      // 48 KB
  __shared__ __bf16 sB[3][64*64];       // 24 KB
  int bid = blockIdx.x;
  int b = bid & 7, r2 = bid >> 3;
  int n = r2 & 3, m = r2 >> 2;          // consecutive bids share the S A-panel
  int m0 = m*128, n0 = n*64;
  int tid = threadIdx.x, lane = tid & 63, w = tid >> 6;
  int lr = lane & 15, kq = lane >> 4;
  int wm = w >> 1, wn = w & 1;
  const __bf16* Ab = S + ((size_t)b*2048 + m0)*1024;            // lda 1024
  const __bf16* Bb = G + ((size_t)b*256 + n0)*2048 + js0;       // ldb 2048
  int bRow = lane >> 3, bSlot = lane & 7;
  f32x4 acc[4][2] = {};
  #pragma unroll
  for (int t0 = 0; t0 < 2; ++t0){
    #pragma unroll
    for (int u = 0; u < 4; ++u){
      int row = u*32 + w*8 + bRow;
      gload16(Ab + (size_t)row*1024 + t0*64 + ((bSlot ^ (row & 7))*8),
              &sA[t0][u*2048 + w*512]);
    }
    #pragma unroll
    for (int u = 0; u < 2; ++u){
      int row = u*32 + w*8 + bRow;
      gload16(Bb + (size_t)row*2048 + t0*64 + ((bSlot ^ (row & 7))*8),
              &sB[t0][u*2048 + w*512]);
    }
  }
  for (int t = 0; t < 16; ++t){
    if (t == 15) asm volatile("s_waitcnt vmcnt(0)" ::: "memory");
    else         asm volatile("s_waitcnt vmcnt(6)" ::: "memory");
    __builtin_amdgcn_s_barrier();
    if (t + 2 < 16){
      int t2 = t + 2, bf2 = t2 % 3, k0 = t2*64;
      #pragma unroll
      for (int u = 0; u < 4; ++u){
        int row = u*32 + w*8 + bRow;
        gload16(Ab + (size_t)row*1024 + k0 + ((bSlot ^ (row & 7))*8),
                &sA[bf2][u*2048 + w*512]);
      }
      #pragma unroll
      for (int u = 0; u < 2; ++u){
        int row = u*32 + w*8 + bRow;
        gload16(Bb + (size_t)row*2048 + k0 + ((bSlot ^ (row & 7))*8),
                &sB[bf2][u*2048 + w*512]);
      }
    }
    const __bf16* Ac = &sA[t % 3][0];
    const __bf16* Bc = &sB[t % 3][0];
    #pragma unroll
    for (int ks = 0; ks < 2; ++ks){
      int slot = ks*4 + kq;
      bf16x8 af[4], bf[2];
      #pragma unroll
      for (int fm = 0; fm < 4; ++fm){
        int ar = wm*64 + fm*16 + lr;
        af[fm] = *(const bf16x8*)&Ac[ar*64 + ((slot ^ (ar & 7))*8)];
      }
      #pragma unroll
      for (int fn = 0; fn < 2; ++fn){
        int br = wn*32 + fn*16 + lr;
        bf[fn] = *(const bf16x8*)&Bc[br*64 + ((slot ^ (br & 7))*8)];
      }
      #pragma unroll
      for (int fm = 0; fm < 4; ++fm)
        #pragma unroll
        for (int fn = 0; fn < 2; ++fn)
          acc[fm][fn] = __builtin_amdgcn_mfma_f32_16x16x32_bf16(af[fm], bf[fn], acc[fm][fn], 0, 0, 0);
    }
  }
  float* Ob = OTacc + (size_t)b*4096*128;
  if (first){
    #pragma unroll
    for (int fm = 0; fm < 4; ++fm)
      #pragma unroll
      for (int fn = 0; fn < 2; ++fn)
        #pragma unroll
        for (int r = 0; r < 4; ++r){
          int i = m0 + wm*64 + fm*16 + kq*4 + r;
          int c = n0 + wn*32 + fn*16 + lr;
          Ob[(size_t)(((c & 1) << 11) + i)*128 + (c >> 1)] = acc[fm][fn][r];
        }
  } else {
    #pragma unroll
    for (int fm = 0; fm < 4; ++fm)
      #pragma unroll
      for (int fn = 0; fn < 2; ++fn)
        #pragma unroll
        for (int r = 0; r < 4; ++r){
          int i = m0 + wm*64 + fm*16 + kq*4 + r;
          int c = n0 + wn*32 + fn*16 + lr;
          size_t idx = (size_t)(((c & 1) << 11) + i)*128 + (c >> 1);
          Ob[idx] += acc[fm][fn][r];
        }
  }
}

// ---------------- mask conv + residual: OTacc(4096x128 f32) * Wm^T(256x128) + x ----------------
__global__ __launch_bounds__(256) void k_mask(const float* OTacc, const __bf16* Wm,
                                              const float* x, float* out){
  __shared__ __bf16 As[128*72];
  __shared__ __bf16 Bs[64*72];
  int b = blockIdx.z, p0 = blockIdx.x*128, o0 = blockIdx.y*64;
  int tid = threadIdx.x, lane = tid & 63, wave = tid >> 6;
  int wm = wave >> 1, wn = wave & 1;
  f32x4 acc[4][2] = {};
  const float* Ab = OTacc + ((size_t)b*4096 + p0)*128;
  const __bf16* Bb = Wm + (size_t)o0*128;
  for (int kc = 0; kc < 2; ++kc){
    int k0 = kc*64;
    #pragma unroll
    for (int it = 0; it < 8; ++it){
      int idx = it*256 + tid;
      int row = idx >> 4, c4 = (idx & 15)*4;
      f32x4 vv = *(const f32x4*)(Ab + (size_t)row*128 + k0 + c4);
      __bf16 tmp[4];
      #pragma unroll
      for (int e = 0; e < 4; ++e) tmp[e] = (__bf16)vv[e];
      *(uint2*)&As[row*72 + c4] = *(const uint2*)tmp;
    }
    #pragma unroll
    for (int itc = 0; itc < 2; ++itc){
      int s = tid + itc*256, row = s >> 3, sk = s & 7;
      *(uint4*)&Bs[row*72 + sk*8] = *(const uint4*)(Bb + (size_t)row*128 + k0 + sk*8);
    }
    __syncthreads();
    #pragma unroll
    for (int ks = 0; ks < 2; ++ks){
      int koff = ks*32 + (lane>>4)*8;
      bf16x8 af[4], bfr[2];
      #pragma unroll
      for (int fm = 0; fm < 4; ++fm)
        af[fm] = *(const bf16x8*)&As[(wm*64 + fm*16 + (lane&15))*72 + koff];
      #pragma unroll
      for (int fn = 0; fn < 2; ++fn)
        bfr[fn] = *(const bf16x8*)&Bs[(wn*32 + fn*16 + (lane&15))*72 + koff];
      #pragma unroll
      for (int fm = 0; fm < 4; ++fm)
        #pragma unroll
        for (int fn = 0; fn < 2; ++fn)
          acc[fm][fn] = __builtin_amdgcn_mfma_f32_16x16x32_bf16(af[fm], bfr[fn], acc[fm][fn], 0, 0, 0);
    }
    __syncthreads();
  }
  #pragma unroll
  for (int fm = 0; fm < 4; ++fm)
    #pragma unroll
    for (int fn = 0; fn < 2; ++fn){
      int pb = p0 + wm*64 + fm*16 + (lane>>4)*4;
      int o = o0 + wn*32 + fn*16 + (lane&15);
      size_t idx = ((size_t)b*256 + o)*4096 + pb;
      f32x4 xv = *(const f32x4*)(x + idx);
      f32x4 ov = acc[fm][fn] + xv;
      *(f32x4*)(out + idx) = ov;
    }
}

extern "C" void kernel_launch(void* const* d_in, const int* in_sizes, int n_in,
                              void* d_out, int out_size, void* d_ws, size_t ws_size,
                              hipStream_t stream){
  if (ws_size < WS_NEED) return;  // workspace too small; fail visibly
  const float* x  = (const float*)d_in[0];
  const float* wt = (const float*)d_in[1];
  const float* wp = (const float*)d_in[2];
  const float* wg = (const float*)d_in[3];
  const float* wm = (const float*)d_in[4];
  char* ws = (char*)d_ws;
  float* OTacc = (float*)(ws + OTA_OFF);
  __bf16* Tt   = (__bf16*)(ws + TT_OFF);
  __bf16* Pt   = (__bf16*)(ws + PT_OFF);
  __bf16* G    = (__bf16*)(ws + G_OFF);
  __bf16* W3   = (__bf16*)(ws + W3_OFF);
  __bf16* Wm   = (__bf16*)(ws + WM_OFF);
  float* invD  = (float*)(ws + ID_OFF);
  float* PART  = (float*)(ws + PART_OFF);
  __bf16* S    = (__bf16*)d_out;           // S slice scratch lives in d_out
  float* out   = (float*)d_out;

  k_weights<<<512, 256, 0, stream>>>(wt, wp, wg, wm, W3, Wm);
  k_conv3x<<<256, 512, 0, stream>>>(x, W3, Tt, Pt, G);
  for (int s = 0; s < 2; ++s){
    int js0 = s * 1024;
    k_sexp<<<256, 512, 0, stream>>>(Tt, Pt, S, PART, js0);
    k_invd<<<32, 256, 0, stream>>>(PART, invD, js0);
    k_gscale<<<2048, 256, 0, stream>>>(G, invD, js0);
    k_pv<<<512, 256, 0, stream>>>(S, G, OTacc, js0, s == 0 ? 1 : 0);
  }
  k_mask<<<dim3(32, 4, 8), 256, 0, stream>>>(OTacc, Wm, x, out);
}